// Round 1
// baseline (651.058 us; speedup 1.0000x reference)
//
#include <hip/hip_runtime.h>

// Prompts: out[row,k] = softmax_k( 100 * dot(x[row,:], tf[k,:]/||tf[k]||) )
// rows = 262144, D = 512, K = 2.
// Traffic floor: read 512 MiB x + write 2 MiB out ~= 82 us @ 6.3 TB/s.
// Round-2 evidence: dur_us dominated by harness poison/restore (2 GiB ws fill
// ~335 us + 512 MiB input restore ~165 us); kernel itself sub-175 us.
// This round: resubmission of the verified-best kernel after an infra-only
// bench failure (container died twice, no counters). Need a clean baseline +
// rocprof capture before touching the reduction structure.

#define D_DIM 512

typedef float vfloat4 __attribute__((ext_vector_type(4)));
typedef float vfloat2 __attribute__((ext_vector_type(2)));

__device__ __forceinline__ float dot4(vfloat4 a, vfloat4 b) {
    return a.x * b.x + a.y * b.y + a.z * b.z + a.w * b.w;
}

__device__ __forceinline__ vfloat4 nt_load4(const vfloat4* p) {
    return __builtin_nontemporal_load(p);
}

__global__ __launch_bounds__(256, 4) void prompts_kernel(
    const float* __restrict__ x,
    const float* __restrict__ tf,
    const float* __restrict__ logit_scale,
    float* __restrict__ out,
    int nrows)
{
    const int lane          = threadIdx.x & 63;
    const int wave_in_block = threadIdx.x >> 6;
    const int gwave  = blockIdx.x * (blockDim.x >> 6) + wave_in_block;
    const int nwaves = gridDim.x * (blockDim.x >> 6);

    // ---- Per-wave weight setup (tf is 4 KiB, cache-resident) ----
    const vfloat4* tf4 = (const vfloat4*)tf;
    vfloat4 w0a = tf4[lane];        // tf row 0, floats [4i, 4i+4)
    vfloat4 w0b = tf4[64 + lane];   // tf row 0, floats [256+4i, ...)
    vfloat4 w1a = tf4[128 + lane];  // tf row 1
    vfloat4 w1b = tf4[192 + lane];

    float ss0 = dot4(w0a, w0a) + dot4(w0b, w0b);
    float ss1 = dot4(w1a, w1a) + dot4(w1b, w1b);
#pragma unroll
    for (int off = 32; off >= 1; off >>= 1) {
        ss0 += __shfl_xor(ss0, off, 64);
        ss1 += __shfl_xor(ss1, off, 64);
    }

    const float scale = expf(logit_scale[0]);   // = 100.0
    const float inv0  = scale / sqrtf(ss0);
    const float inv1  = scale / sqrtf(ss1);

    w0a *= inv0; w0b *= inv0;
    w1a *= inv1; w1b *= inv1;

    // ---- Persistent grid-stride, 4 rows (8 KiB) per wave-iteration ----
    const vfloat4* x4   = (const vfloat4*)x;
    vfloat2*       out2 = (vfloat2*)out;

    for (int row0 = gwave * 4; row0 < nrows; row0 += nwaves * 4) {
        const vfloat4* p = x4 + (size_t)row0 * (D_DIM / 4);

        // 8 independent nontemporal 16B loads (x is touched exactly once)
        vfloat4 xa0 = nt_load4(p + lane      ), xb0 = nt_load4(p + lane +  64);
        vfloat4 xa1 = nt_load4(p + lane + 128), xb1 = nt_load4(p + lane + 192);
        vfloat4 xa2 = nt_load4(p + lane + 256), xb2 = nt_load4(p + lane + 320);
        vfloat4 xa3 = nt_load4(p + lane + 384), xb3 = nt_load4(p + lane + 448);

        float s00 = dot4(xa0, w0a) + dot4(xb0, w0b);
        float s10 = dot4(xa0, w1a) + dot4(xb0, w1b);
        float s01 = dot4(xa1, w0a) + dot4(xb1, w0b);
        float s11 = dot4(xa1, w1a) + dot4(xb1, w1b);
        float s02 = dot4(xa2, w0a) + dot4(xb2, w0b);
        float s12 = dot4(xa2, w1a) + dot4(xb2, w1b);
        float s03 = dot4(xa3, w0a) + dot4(xb3, w0b);
        float s13 = dot4(xa3, w1a) + dot4(xb3, w1b);

#pragma unroll
        for (int off = 32; off >= 1; off >>= 1) {
            s00 += __shfl_xor(s00, off, 64);
            s10 += __shfl_xor(s10, off, 64);
            s01 += __shfl_xor(s01, off, 64);
            s11 += __shfl_xor(s11, off, 64);
            s02 += __shfl_xor(s02, off, 64);
            s12 += __shfl_xor(s12, off, 64);
            s03 += __shfl_xor(s03, off, 64);
            s13 += __shfl_xor(s13, off, 64);
        }

        if (lane < 4) {
            float a = s00, b = s10;
            if      (lane == 1) { a = s01; b = s11; }
            else if (lane == 2) { a = s02; b = s12; }
            else if (lane == 3) { a = s03; b = s13; }
            // softmax over 2: overflow-safe (exp->inf => p->0)
            vfloat2 pr;
            pr.x = 1.0f / (1.0f + expf(b - a));
            pr.y = 1.0f / (1.0f + expf(a - b));
            __builtin_nontemporal_store(pr, out2 + row0 + lane);
        }
    }
}

extern "C" void kernel_launch(void* const* d_in, const int* in_sizes, int n_in,
                              void* d_out, int out_size, void* d_ws, size_t ws_size,
                              hipStream_t stream) {
    const float* x  = (const float*)d_in[0];
    const float* tf = (const float*)d_in[1];
    const float* ls = (const float*)d_in[2];
    float* out = (float*)d_out;

    const int nrows = in_sizes[0] / D_DIM;  // 262144

    // 1024 blocks x 256 thr = 4096 waves; 4 blocks/CU co-resident (128 VGPR),
    // one pass, 16 iterations per wave, 64 KiB of loads in flight per CU.
    prompts_kernel<<<1024, 256, 0, stream>>>(x, tf, ls, out, nrows);
}

// Round 2
// 647.553 us; speedup vs baseline: 1.0054x; 1.0054x over previous
//
#include <hip/hip_runtime.h>

// Prompts: out[row,k] = softmax_k( 100 * dot(x[row,:], tf[k,:]/||tf[k]||) )
// rows = 262144, D = 512, K = 2.
// Traffic floor: read 512 MiB x + write 2 MiB out ~= 82 us @ 6.3 TB/s.
// Harness fixed cost (measured r1): 2 GiB ws poison ~335 us @6.4TB/s + input
// restore ~165 us => ~500 us of the 651 us headline. Kernel itself ~150 us.
// This round: 16-lane-group-per-row layout. Cuts the cross-lane reduce from
// 48 ds_swizzle / 6 dependent stages per 4 rows to 8 ds_swizzle / 4 stages,
// and lets dot(j) consume load(j) incrementally instead of waiting on all 8.
// Target: kernel ~150 -> ~100 us, headline ~600 us.

#define D_DIM 512

typedef float vfloat4 __attribute__((ext_vector_type(4)));
typedef float vfloat2 __attribute__((ext_vector_type(2)));

__device__ __forceinline__ float dot4(vfloat4 a, vfloat4 b) {
    return a.x * b.x + a.y * b.y + a.z * b.z + a.w * b.w;
}

__device__ __forceinline__ vfloat4 nt_load4(const vfloat4* p) {
    return __builtin_nontemporal_load(p);
}

__global__ __launch_bounds__(256, 4) void prompts_kernel(
    const float* __restrict__ x,
    const float* __restrict__ tf,
    const float* __restrict__ logit_scale,
    float* __restrict__ out,
    int nrows)
{
    const int lane          = threadIdx.x & 63;
    const int t             = lane & 15;   // sublane within 16-lane group
    const int g             = lane >> 4;   // group 0..3; group owns one row
    const int wave_in_block = threadIdx.x >> 6;
    const int gwave  = blockIdx.x * (blockDim.x >> 6) + wave_in_block;
    const int nwaves = gridDim.x * (blockDim.x >> 6);

    // ---- Weights: sublane t keeps slices t+16j (j=0..7) of both tf rows
    //      in registers (tf is 4 KiB, L1-resident; one-time setup).
    const vfloat4* tf4 = (const vfloat4*)tf;
    vfloat4 w0[8], w1[8];
#pragma unroll
    for (int j = 0; j < 8; ++j) {
        w0[j] = tf4[t + 16 * j];
        w1[j] = tf4[128 + t + 16 * j];
    }

    float ss0 = 0.f, ss1 = 0.f;
#pragma unroll
    for (int j = 0; j < 8; ++j) {
        ss0 += dot4(w0[j], w0[j]);
        ss1 += dot4(w1[j], w1[j]);
    }
#pragma unroll
    for (int off = 8; off >= 1; off >>= 1) {   // reduce across the 16 sublanes
        ss0 += __shfl_xor(ss0, off, 64);
        ss1 += __shfl_xor(ss1, off, 64);
    }

    const float scale = expf(logit_scale[0]);  // = 100.0
    const float inv0  = scale / sqrtf(ss0);
    const float inv1  = scale / sqrtf(ss1);
#pragma unroll
    for (int j = 0; j < 8; ++j) { w0[j] *= inv0; w1[j] *= inv1; }

    // ---- Persistent grid-stride: 4 rows (8 KiB) per wave-iteration,
    //      one row per 16-lane group.
    const vfloat4* x4   = (const vfloat4*)x;
    vfloat2*       out2 = (vfloat2*)out;

    for (int row0 = gwave * 4; row0 < nrows; row0 += nwaves * 4) {
        const vfloat4* p = x4 + (size_t)(row0 + g) * (D_DIM / 4) + t;

        // 8 independent nontemporal 16B loads; per instruction the wave
        // touches 4 contiguous 256B segments (one per group) -- coalesced.
        vfloat4 xv[8];
#pragma unroll
        for (int j = 0; j < 8; ++j) xv[j] = nt_load4(p + 16 * j);

        // dot(j) depends only on load(j): compiler interleaves vmcnt(7..0).
        float d0[8], d1[8];
#pragma unroll
        for (int j = 0; j < 8; ++j) {
            d0[j] = dot4(xv[j], w0[j]);
            d1[j] = dot4(xv[j], w1[j]);
        }
        float a = ((d0[0] + d0[1]) + (d0[2] + d0[3]))
                + ((d0[4] + d0[5]) + (d0[6] + d0[7]));
        float b = ((d1[0] + d1[1]) + (d1[2] + d1[3]))
                + ((d1[4] + d1[5]) + (d1[6] + d1[7]));

        // 4-stage butterfly within the 16-lane group (was 6 stages x 8 vals).
#pragma unroll
        for (int off = 8; off >= 1; off >>= 1) {
            a += __shfl_xor(a, off, 64);
            b += __shfl_xor(b, off, 64);
        }

        if (t == 0) {
            // softmax over 2: overflow-safe (exp->inf => p->0)
            vfloat2 pr;
            pr.x = 1.0f / (1.0f + expf(b - a));
            pr.y = 1.0f / (1.0f + expf(a - b));
            __builtin_nontemporal_store(pr, out2 + row0 + g);
        }
    }
}

extern "C" void kernel_launch(void* const* d_in, const int* in_sizes, int n_in,
                              void* d_out, int out_size, void* d_ws, size_t ws_size,
                              hipStream_t stream) {
    const float* x  = (const float*)d_in[0];
    const float* tf = (const float*)d_in[1];
    const float* ls = (const float*)d_in[2];
    float* out = (float*)d_out;

    const int nrows = in_sizes[0] / D_DIM;  // 262144

    // 1024 blocks x 256 thr = 4096 waves; 4 blocks/CU co-resident (<=128 VGPR),
    // 16 iterations per wave, 4 rows per wave-iteration.
    prompts_kernel<<<1024, 256, 0, stream>>>(x, tf, ls, out, nrows);
}